// Round 7
// baseline (783.499 us; speedup 1.0000x reference)
//
#include <hip/hip_runtime.h>

// ---------------------------------------------------------------------------
// GraphTrajSimEncoder on MI355X — round 7.
// R6 post-mortem: k_agg balanced-stalled (VALU 45%, L2-miss 3.3TB/s, occ 75%).
// Changes: (1) float2/pk_fma accumulation in k_agg (~35% VALU cut);
// (2) 1D agg grid, set=blockIdx.x&1 -> set->XCD affinity for layer-1 tables;
// (3) k_prep folded into k_scan2 (dinv/cur from in-register scan values);
// single memset over contiguous cnt0|cnt1.
// ---------------------------------------------------------------------------

using bf16x8  = __attribute__((ext_vector_type(8))) __bf16;
using floatx4 = __attribute__((ext_vector_type(4))) float;
using f32x2   = __attribute__((ext_vector_type(2))) float;

__device__ __forceinline__ float b2f(unsigned short b) {
    return __uint_as_float(((unsigned)b) << 16);
}
__device__ __forceinline__ unsigned short f2b(float f) {
    unsigned u = __float_as_uint(f);
    return (unsigned short)((u + 0x7FFFu + ((u >> 16) & 1u)) >> 16);
}
__device__ __forceinline__ unsigned short f2h(float f) {
    _Float16 h = (_Float16)f;
    return __builtin_bit_cast(unsigned short, h);
}
__device__ __forceinline__ float h2f(unsigned short u) {
    return (float)__builtin_bit_cast(_Float16, u);
}

// ---------------- graph preprocessing ----------------

__global__ void k_cnt2(const int* __restrict__ col0, const int* __restrict__ col1,
                       int E, int* __restrict__ cnt0, int* __restrict__ cnt1) {
    int e = blockIdx.x * 256 + threadIdx.x;
    const int* col = blockIdx.y ? col1 : col0;
    int* cnt = blockIdx.y ? cnt1 : cnt0;
    if (e < E) atomicAdd(&cnt[col[e]], 1);
}

// grid (1,2): one block per set. Scans PADDED counts (round to 8):
// off[0]=0, off[i+1]=incl-scan; also emits cur[i]=excl-scan (CSR fill cursor)
// and dinv[i]=rsqrt(raw_deg+1) from in-register values (no global re-read).
__global__ __launch_bounds__(1024) void k_scan2(
    const int* __restrict__ cnt0, const int* __restrict__ cnt1,
    int* __restrict__ off0, int* __restrict__ off1,
    int* __restrict__ cur0, int* __restrict__ cur1,
    float* __restrict__ dinv0, float* __restrict__ dinv1, int n) {
    const int* cnt = blockIdx.y ? cnt1 : cnt0;
    int* off = blockIdx.y ? off1 : off0;
    int* cur = blockIdx.y ? cur1 : cur0;
    float* dinv = blockIdx.y ? dinv1 : dinv0;
    __shared__ int wsum[16];
    __shared__ int wpre[16];
    __shared__ int carry;
    const int t = threadIdx.x;
    const int lane = t & 63;
    const int w = t >> 6;
    if (t == 0) { carry = 0; off[0] = 0; }
    __syncthreads();
    for (int base = 0; base < n; base += 1024) {
        int i = base + t;
        int raw = (i < n) ? cnt[i] : 0;
        int vpad = (raw + 7) & ~7;                 // pad each node to x8
        int v = vpad;
        #pragma unroll
        for (int d = 1; d < 64; d <<= 1) {
            int u = __shfl_up(v, d, 64);
            if (lane >= d) v += u;
        }
        if (lane == 63) wsum[w] = v;
        __syncthreads();
        if (t < 16) {
            int s = wsum[t];
            #pragma unroll
            for (int d = 1; d < 16; d <<= 1) {
                int u = __shfl_up(s, d, 16);
                if (t >= d) s += u;
            }
            wpre[t] = s;
        }
        __syncthreads();
        int add = carry + (w > 0 ? wpre[w - 1] : 0);
        if (i < n) {
            int incl = v + add;
            off[i + 1] = incl;
            cur[i] = incl - vpad;                  // exclusive prefix
            dinv[i] = rsqrtf((float)(raw + 1));
        }
        __syncthreads();
        if (t == 0) carry += wpre[15];
        __syncthreads();
    }
}

// CSR fill: 8B record per edge = (src:u32, (fp16 w1)<<16 | fp16 w2).
__global__ void k_fill2(const int* __restrict__ ei0, const float* __restrict__ ea0,
                        const int* __restrict__ ei1, const float* __restrict__ ea1,
                        int E, const float* __restrict__ dinv0,
                        const float* __restrict__ dinv1,
                        int* __restrict__ cur0, int* __restrict__ cur1,
                        uint2* __restrict__ rec0, uint2* __restrict__ rec1) {
    int e = blockIdx.x * 256 + threadIdx.x;
    if (e >= E) return;
    const int* ei = blockIdx.y ? ei1 : ei0;
    const float* ea = blockIdx.y ? ea1 : ea0;
    const float* dinv = blockIdx.y ? dinv1 : dinv0;
    int* cur = blockIdx.y ? cur1 : cur0;
    uint2* rec = blockIdx.y ? rec1 : rec0;
    int r = ei[e];          // source
    int c = ei[E + e];      // target
    float a = ea[e];
    float w2 = (a > 0.0f) ? fminf(rsqrtf(a), 1.0f) : 0.0f;
    float w1 = dinv[r] * dinv[c];
    int p = atomicAdd(&cur[c], 1);
    rec[p] = make_uint2((unsigned)r,
                        ((unsigned)f2h(w1) << 16) | (unsigned)f2h(w2));
}

// pad tail slots with (row 0, zero weights) — grid (gN,2)
__global__ void k_pad(const int* __restrict__ cnt0, const int* __restrict__ cnt1,
                      const int* __restrict__ off0, const int* __restrict__ off1,
                      uint2* __restrict__ rec0, uint2* __restrict__ rec1, int n) {
    int i = blockIdx.x * 256 + threadIdx.x;
    if (i >= n) return;
    const int* cnt = blockIdx.y ? cnt1 : cnt0;
    const int* off = blockIdx.y ? off1 : off0;
    uint2* rec = blockIdx.y ? rec1 : rec0;
    int p = off[i] + cnt[i], pe = off[i + 1];
    for (; p < pe; ++p) rec[p] = make_uint2(0u, 0u);
}

// ---------------- dtype conversions ----------------

// xc[i][k] (bf16, K padded to KP): k<F -> x, k<KC -> d2an, else 0  (row-major)
__global__ void k_xc(const float* __restrict__ x, const float* __restrict__ pe,
                     unsigned short* __restrict__ xc, int n, int F, int PEd,
                     int KC, int KP) {
    int idx = blockIdx.x * 256 + threadIdx.x;
    if (idx >= n * KP) return;
    int i = idx / KP, k = idx - i * KP;
    float v = 0.0f;
    if (k < F)        v = x[(size_t)i * F + k];
    else if (k < KC)  v = pe[(size_t)i * PEd + (k - F)];
    xc[idx] = f2b(v);
}

// weight conversions (row-major K):
//   seg 0/1: Wn [F][KC] f32 -> [F][KP] bf16 zero-padded
//   seg 2..5: [Wa|Wb] pairs -> [F][512] bf16 plain concat
__global__ void k_wall(const float* __restrict__ Wn1, const float* __restrict__ Wn2,
                       const float* __restrict__ W11, const float* __restrict__ W12,
                       const float* __restrict__ W21, const float* __restrict__ W22,
                       const float* __restrict__ W31, const float* __restrict__ W32,
                       const float* __restrict__ W41, const float* __restrict__ W42,
                       unsigned short* __restrict__ wn0c, unsigned short* __restrict__ wn1c,
                       unsigned short* __restrict__ wc0, unsigned short* __restrict__ wc1,
                       unsigned short* __restrict__ wc2, unsigned short* __restrict__ wc3,
                       int F, int KC, int KP) {
    int idx = blockIdx.x * 256 + threadIdx.x;
    int npad = F * KP;
    if (idx < 2 * npad) {
        const float* W = (idx < npad) ? Wn1 : Wn2;
        unsigned short* Wc = (idx < npad) ? wn0c : wn1c;
        int t = (idx < npad) ? idx : idx - npad;
        int o = t / KP, k = t - o * KP;
        Wc[t] = f2b(k < KC ? W[(size_t)o * KC + k] : 0.0f);
        return;
    }
    int t = idx - 2 * npad;
    int seg = F * 512;
    if (t >= 4 * seg) return;
    int which = t / seg;
    int r = t - which * seg;
    const float* Wa = (which == 0) ? W11 : (which == 1) ? W21 : (which == 2) ? W31 : W41;
    const float* Wb = (which == 0) ? W12 : (which == 1) ? W22 : (which == 2) ? W32 : W42;
    unsigned short* Wc = (which == 0) ? wc0 : (which == 1) ? wc1 : (which == 2) ? wc2 : wc3;
    int o = r >> 9, k = r & 511;
    float v = (k < 256) ? Wa[(size_t)o * 256 + k] : Wb[(size_t)o * 256 + (k - 256)];
    Wc[r] = f2b(v);
}

// ---------------- CSR gather-aggregation (scalarized, packed FMA) ----------
// 1D grid: set = blockIdx.x & 1 (round-robin block->XCD puts each layer-1
// table mostly on its own XCD parity — perf heuristic only). One wave per
// node, full wave per edge (uint2 = 4 bf16/lane). Uniform record loads,
// readfirstlane'd row index -> saddr gathers. CSR padded to x8 (no tails).
// Accumulation in float2 ext-vectors -> v_pk_fma_f32.
__global__ __launch_bounds__(256) void k_agg(
    const unsigned short* __restrict__ X0, const unsigned short* __restrict__ X1,
    const int* __restrict__ off0, const int* __restrict__ off1,
    const uint2* __restrict__ rec0, const uint2* __restrict__ rec1,
    const float* __restrict__ dinv0, const float* __restrict__ dinv1,
    unsigned short* __restrict__ A0, unsigned short* __restrict__ A1, int n) {
    const int s = blockIdx.x & 1;
    const unsigned short* X = s ? X1 : X0;
    const int* off = s ? off1 : off0;
    const uint2* rec = s ? rec1 : rec0;
    const float* dinv = s ? dinv1 : dinv0;
    unsigned short* A = s ? A1 : A0;

    const int wave = threadIdx.x >> 6;
    const int lane = threadIdx.x & 63;
    const int gw = (blockIdx.x >> 1) * 4 + wave;
    if (gw >= n) return;

    const int e0 = __builtin_amdgcn_readfirstlane(off[gw]);
    const int e1 = __builtin_amdgcn_readfirstlane(off[gw + 1]);
    const float di = dinv[gw];
    const uint2* X2 = (const uint2*)X;               // 4 bf16 per uint2
    uint2 xs = X2[(size_t)gw * 64 + lane];           // self row

    f32x2 a1lo = {0.f, 0.f}, a1hi = {0.f, 0.f};
    f32x2 a2lo = {0.f, 0.f}, a2hi = {0.f, 0.f};

    for (int base = e0; base < e1; base += 8) {
        uint2 rr[8];
        #pragma unroll
        for (int k = 0; k < 8; k++) rr[k] = rec[base + k];   // uniform
        uint2 g[8];
        #pragma unroll
        for (int k = 0; k < 8; k++) {
            unsigned src = (unsigned)__builtin_amdgcn_readfirstlane(rr[k].x);
            g[k] = X2[(size_t)src * 64 + lane];              // saddr gather
        }
        #pragma unroll
        for (int k = 0; k < 8; k++) {
            float w1 = h2f((unsigned short)(rr[k].y >> 16));
            float w2 = h2f((unsigned short)(rr[k].y & 0xFFFFu));
            f32x2 w1v = {w1, w1}, w2v = {w2, w2};
            f32x2 plo = {__uint_as_float(g[k].x << 16),
                         __uint_as_float(g[k].x & 0xFFFF0000u)};
            f32x2 phi = {__uint_as_float(g[k].y << 16),
                         __uint_as_float(g[k].y & 0xFFFF0000u)};
            a1lo += w1v * plo; a1hi += w1v * phi;            // v_pk_fma_f32
            a2lo += w2v * plo; a2hi += w2v * phi;
        }
    }

    // self loop: deg_norm = di*di, edge_norm = 1
    {
        f32x2 plo = {__uint_as_float(xs.x << 16),
                     __uint_as_float(xs.x & 0xFFFF0000u)};
        f32x2 phi = {__uint_as_float(xs.y << 16),
                     __uint_as_float(xs.y & 0xFFFF0000u)};
        float ws = di * di;
        f32x2 wsv = {ws, ws};
        a1lo += wsv * plo; a1hi += wsv * phi;
        a2lo += plo;       a2hi += phi;
    }

    uint2 o1, o2;
    o1.x = (unsigned)f2b(a1lo.x) | ((unsigned)f2b(a1lo.y) << 16);
    o1.y = (unsigned)f2b(a1hi.x) | ((unsigned)f2b(a1hi.y) << 16);
    o2.x = (unsigned)f2b(a2lo.x) | ((unsigned)f2b(a2lo.y) << 16);
    o2.y = (unsigned)f2b(a2hi.x) | ((unsigned)f2b(a2hi.y) << 16);
    *(uint2*)(A + (size_t)gw * 512 + lane * 4) = o1;
    *(uint2*)(A + (size_t)gw * 512 + 256 + lane * 4) = o2;
}

// ---------------- bf16 MFMA GEMM kernels ----------------
#define GLL(g, l) \
    __builtin_amdgcn_global_load_lds((__attribute__((address_space(1))) void*)(g), \
                                     (__attribute__((address_space(3))) void*)(l), 16, 0, 0)

// node-transform GEMM: C[M][Nc] = A[M][K] @ B[Nc][K]^T, bf16 out, z selects B/out.
__global__ __launch_bounds__(256) void gemm_bt(
    const unsigned short* __restrict__ A,
    const unsigned short* __restrict__ B0, const unsigned short* __restrict__ B1,
    int M, int K, int Nc,
    unsigned short* __restrict__ outH0, unsigned short* __restrict__ outH1) {
    const unsigned short* B = blockIdx.z ? B1 : B0;
    unsigned short* outH = blockIdx.z ? outH1 : outH0;

    __shared__ __align__(16) unsigned short sA[128 * 32];
    __shared__ __align__(16) unsigned short sB[128 * 32];
    const int tid = threadIdx.x;
    const int lane = tid & 63;
    const int wave = tid >> 6;
    const int bm = blockIdx.x * 128;
    const int bn = blockIdx.y * 128;

    const int r0 = wave * 32 + (lane >> 2);
    const int kcol = (lane & 3) * 8;
    const int ga0 = min(bm + r0, M - 1);
    const int ga1 = min(bm + r0 + 16, M - 1);
    const int gb0 = min(bn + r0, Nc - 1);
    const int gb1 = min(bn + r0 + 16, Nc - 1);
    const unsigned short* pa0 = A + (size_t)ga0 * K + kcol;
    const unsigned short* pa1 = A + (size_t)ga1 * K + kcol;
    const unsigned short* pb0 = B + (size_t)gb0 * K + kcol;
    const unsigned short* pb1 = B + (size_t)gb1 * K + kcol;
    unsigned short* la0 = &sA[wave * 1024];
    unsigned short* la1 = &sA[wave * 1024 + 512];
    unsigned short* lb0 = &sB[wave * 1024];
    unsigned short* lb1 = &sB[wave * 1024 + 512];

    floatx4 acc[4][4];
    #pragma unroll
    for (int i = 0; i < 4; i++)
        #pragma unroll
        for (int j = 0; j < 4; j++) acc[i][j] = (floatx4){0.f, 0.f, 0.f, 0.f};

    const int mbase = (wave & 1) * 64 + (lane & 15);
    const int nbase = (wave >> 1) * 64 + (lane & 15);
    const int koff = (lane >> 4) * 8;

    for (int kk = 0; kk < K; kk += 32) {
        GLL(pa0 + kk, la0);
        GLL(pa1 + kk, la1);
        GLL(pb0 + kk, lb0);
        GLL(pb1 + kk, lb1);
        __syncthreads();
        bf16x8 af[4], bf[4];
        #pragma unroll
        for (int mi = 0; mi < 4; mi++)
            af[mi] = *(const bf16x8*)&sA[(mbase + mi * 16) * 32 + koff];
        #pragma unroll
        for (int ni = 0; ni < 4; ni++)
            bf[ni] = *(const bf16x8*)&sB[(nbase + ni * 16) * 32 + koff];
        #pragma unroll
        for (int mi = 0; mi < 4; mi++)
            #pragma unroll
            for (int ni = 0; ni < 4; ni++)
                acc[mi][ni] = __builtin_amdgcn_mfma_f32_16x16x32_bf16(
                    af[mi], bf[ni], acc[mi][ni], 0, 0, 0);
        __syncthreads();
    }

    const int crow = bm + (wave & 1) * 64 + (lane >> 4) * 4;
    const int ccol = bn + (wave >> 1) * 64 + (lane & 15);
    #pragma unroll
    for (int mi = 0; mi < 4; mi++)
        #pragma unroll
        for (int ni = 0; ni < 4; ni++)
            #pragma unroll
            for (int r = 0; r < 4; r++) {
                int row = crow + mi * 16 + r;
                if (row >= M) continue;
                int col = ccol + ni * 16;
                outH[(size_t)row * Nc + col] = f2b(acc[mi][ni][r]);
            }
}

// dual GEMM: C = 0.5*relu(A0@B0^T) + 0.5*relu(A1@B1^T); out f32 or bf16.
__global__ __launch_bounds__(256) void gemm_dual(
    const unsigned short* __restrict__ A0, const unsigned short* __restrict__ B0,
    const unsigned short* __restrict__ A1, const unsigned short* __restrict__ B1,
    int M, int K, int Nc,
    float* __restrict__ outF, unsigned short* __restrict__ outH, float alpha) {
    __shared__ __align__(16) unsigned short sA[128 * 32];
    __shared__ __align__(16) unsigned short sB[128 * 32];
    const int tid = threadIdx.x;
    const int lane = tid & 63;
    const int wave = tid >> 6;
    const int bm = blockIdx.x * 128;
    const int bn = blockIdx.y * 128;

    const int r0 = wave * 32 + (lane >> 2);
    const int kcol = (lane & 3) * 8;
    const int ga0 = min(bm + r0, M - 1);
    const int ga1 = min(bm + r0 + 16, M - 1);
    const int gb0 = min(bn + r0, Nc - 1);
    const int gb1 = min(bn + r0 + 16, Nc - 1);
    unsigned short* la0 = &sA[wave * 1024];
    unsigned short* la1 = &sA[wave * 1024 + 512];
    unsigned short* lb0 = &sB[wave * 1024];
    unsigned short* lb1 = &sB[wave * 1024 + 512];

    const int mbase = (wave & 1) * 64 + (lane & 15);
    const int nbase = (wave >> 1) * 64 + (lane & 15);
    const int koff = (lane >> 4) * 8;

    floatx4 acc[4][4], res[4][4];

    #pragma unroll
    for (int pass = 0; pass < 2; pass++) {
        const unsigned short* A = pass ? A1 : A0;
        const unsigned short* B = pass ? B1 : B0;
        const unsigned short* pa0 = A + (size_t)ga0 * K + kcol;
        const unsigned short* pa1 = A + (size_t)ga1 * K + kcol;
        const unsigned short* pb0 = B + (size_t)gb0 * K + kcol;
        const unsigned short* pb1 = B + (size_t)gb1 * K + kcol;
        #pragma unroll
        for (int i = 0; i < 4; i++)
            #pragma unroll
            for (int j = 0; j < 4; j++) acc[i][j] = (floatx4){0.f, 0.f, 0.f, 0.f};

        for (int kk = 0; kk < K; kk += 32) {
            GLL(pa0 + kk, la0);
            GLL(pa1 + kk, la1);
            GLL(pb0 + kk, lb0);
            GLL(pb1 + kk, lb1);
            __syncthreads();
            bf16x8 af[4], bf[4];
            #pragma unroll
            for (int mi = 0; mi < 4; mi++)
                af[mi] = *(const bf16x8*)&sA[(mbase + mi * 16) * 32 + koff];
            #pragma unroll
            for (int ni = 0; ni < 4; ni++)
                bf[ni] = *(const bf16x8*)&sB[(nbase + ni * 16) * 32 + koff];
            #pragma unroll
            for (int mi = 0; mi < 4; mi++)
                #pragma unroll
                for (int ni = 0; ni < 4; ni++)
                    acc[mi][ni] = __builtin_amdgcn_mfma_f32_16x16x32_bf16(
                        af[mi], bf[ni], acc[mi][ni], 0, 0, 0);
            __syncthreads();
        }
        if (pass == 0) {
            #pragma unroll
            for (int mi = 0; mi < 4; mi++)
                #pragma unroll
                for (int ni = 0; ni < 4; ni++)
                    #pragma unroll
                    for (int r = 0; r < 4; r++)
                        res[mi][ni][r] = fmaxf(acc[mi][ni][r], 0.0f);
        }
    }

    const int crow = bm + (wave & 1) * 64 + (lane >> 4) * 4;
    const int ccol = bn + (wave >> 1) * 64 + (lane & 15);
    #pragma unroll
    for (int mi = 0; mi < 4; mi++)
        #pragma unroll
        for (int ni = 0; ni < 4; ni++)
            #pragma unroll
            for (int r = 0; r < 4; r++) {
                int row = crow + mi * 16 + r;
                if (row >= M) continue;
                int col = ccol + ni * 16;
                float v = alpha * (res[mi][ni][r] + fmaxf(acc[mi][ni][r], 0.0f));
                size_t idx = (size_t)row * Nc + col;
                if (outF) outF[idx] = v;
                else      outH[idx] = f2b(v);
            }
}

// ---------------- host orchestration ----------------

extern "C" void kernel_launch(void* const* d_in, const int* in_sizes, int n_in,
                              void* d_out, int out_size, void* d_ws, size_t ws_size,
                              hipStream_t stream) {
    const int F = 256;
    const int N = in_sizes[0] / F;
    const int PEd = in_sizes[1] / N;          // 98
    const int E = in_sizes[2] / 2;            // 800000
    const int KC = F + PEd;                   // 354
    const int KP = (KC + 31) & ~31;           // 384

    const float* x   = (const float*)d_in[0];
    const float* pe  = (const float*)d_in[1];
    const int*   ei0 = (const int*)d_in[2];
    const float* ea0 = (const float*)d_in[3];
    const int*   ei1 = (const int*)d_in[4];
    const float* ea1 = (const float*)d_in[5];
    const float* Wn1 = (const float*)d_in[6];
    const float* Wn2 = (const float*)d_in[7];
    const float* W11 = (const float*)d_in[8];
    const float* W12 = (const float*)d_in[9];
    const float* W21 = (const float*)d_in[10];
    const float* W22 = (const float*)d_in[11];
    const float* W31 = (const float*)d_in[12];
    const float* W32 = (const float*)d_in[13];
    const float* W41 = (const float*)d_in[14];
    const float* W42 = (const float*)d_in[15];
    float* out = (float*)d_out;

    char* p = (char*)d_ws;
    auto alloc = [&](size_t b) -> char* {
        char* r = p;
        p += (b + 255) & ~(size_t)255;
        return r;
    };
    int*   cnt01 = (int*)alloc((size_t)2 * N * 4);   // cnt0|cnt1 contiguous
    int*   cnt0  = cnt01;
    int*   cnt1  = cnt01 + N;
    int*   off0  = (int*)alloc((size_t)(N + 1) * 4);
    int*   off1  = (int*)alloc((size_t)(N + 1) * 4);
    int*   cur0  = (int*)alloc((size_t)N * 4);
    int*   cur1  = (int*)alloc((size_t)N * 4);
    float* dinv0 = (float*)alloc((size_t)N * 4);
    float* dinv1 = (float*)alloc((size_t)N * 4);
    uint2* rec0  = (uint2*)alloc(((size_t)E + 8ull * N) * 8);   // padded CSR
    uint2* rec1  = (uint2*)alloc(((size_t)E + 8ull * N) * 8);
    unsigned short* wn0c = (unsigned short*)alloc((size_t)F * KP * 2);
    unsigned short* wn1c = (unsigned short*)alloc((size_t)F * KP * 2);
    unsigned short* wc0  = (unsigned short*)alloc((size_t)F * 512 * 2);
    unsigned short* wc1  = (unsigned short*)alloc((size_t)F * 512 * 2);
    unsigned short* wc2  = (unsigned short*)alloc((size_t)F * 512 * 2);
    unsigned short* wc3  = (unsigned short*)alloc((size_t)F * 512 * 2);
    unsigned short* xa   = (unsigned short*)alloc((size_t)N * 512 * 2);  // xa|xb
    unsigned short* xb   = xa + (size_t)N * 256;
    unsigned short* h    = (unsigned short*)alloc((size_t)N * F * 2);
    unsigned short* a12  = (unsigned short*)alloc((size_t)N * 512 * 2);
    unsigned short* xc   = a12;                  // dead after node transforms
    unsigned short* a12bL1 = (unsigned short*)d_out;  // N*512 bf16 == out_size f32
    unsigned short* a12bL2 = xa;                 // xa|xb dead after layer-1 agg

    const int B = 256;
    const int gE = (E + B - 1) / B;
    const int gN = (N + B - 1) / B;
    const int gAgg = 2 * ((N + 3) / 4);          // 1D: set = bx&1, 4 nodes/block
    dim3 gemm_grid((N + 127) / 128, 2);
    dim3 gemm_grid2((N + 127) / 128, 2, 2);

    // 1. degree / dinv / padded CSR
    hipMemsetAsync(cnt01, 0, (size_t)2 * N * 4, stream);
    k_cnt2<<<dim3(gE, 2), B, 0, stream>>>(ei0 + E, ei1 + E, E, cnt0, cnt1);
    k_scan2<<<dim3(1, 2), 1024, 0, stream>>>(cnt0, cnt1, off0, off1,
                                             cur0, cur1, dinv0, dinv1, N);
    k_fill2<<<dim3(gE, 2), B, 0, stream>>>(ei0, ea0, ei1, ea1, E, dinv0, dinv1,
                                           cur0, cur1, rec0, rec1);
    k_pad<<<dim3(gN, 2), B, 0, stream>>>(cnt0, cnt1, off0, off1, rec0, rec1, N);

    // 2. bf16 conversions
    k_xc<<<((size_t)N * KP + B - 1) / B, B, 0, stream>>>(x, pe, xc, N, F, PEd, KC, KP);
    {
        int tot = 2 * F * KP + 4 * F * 512;
        k_wall<<<(tot + B - 1) / B, B, 0, stream>>>(Wn1, Wn2, W11, W12, W21, W22,
                                                    W31, W32, W41, W42,
                                                    wn0c, wn1c, wc0, wc1, wc2, wc3,
                                                    F, KC, KP);
    }

    // 3. node transforms (both via blockIdx.z) -> xa, xb  [row-major N x 256]
    gemm_bt<<<gemm_grid2, B, 0, stream>>>(xc, wn0c, wn1c, N, KP, F, xa, xb);

    // 4. layer 1: both aggs in one dispatch; then dual GEMM -> h (bf16)
    k_agg<<<gAgg, B, 0, stream>>>(xa, xb, off0, off1, rec0, rec1,
                                  dinv0, dinv1, a12, a12bL1, N);
    gemm_dual<<<gemm_grid, B, 0, stream>>>(a12, wc0, a12bL1, wc1, N, 512, F,
                                           nullptr, h, 0.5f);

    // 5. layer 2: both aggs in one dispatch; then dual GEMM -> out (f32)
    k_agg<<<gAgg, B, 0, stream>>>(h, h, off0, off1, rec0, rec1,
                                  dinv0, dinv1, a12, a12bL2, N);
    gemm_dual<<<gemm_grid, B, 0, stream>>>(a12, wc2, a12bL2, wc3, N, 512, F,
                                           out, nullptr, 0.5f);
}